// Round 2
// baseline (2605.521 us; speedup 1.0000x reference)
//
#include <hip/hip_runtime.h>
#include <hip/hip_bf16.h>

#define NPOS 262144   // 4 * 256 * 256

typedef short bf16x8 __attribute__((ext_vector_type(8)));
typedef float f32x4 __attribute__((ext_vector_type(4)));

__device__ __forceinline__ unsigned short f2bf(float f) {
    union { float f; unsigned u; } v; v.f = f;
    unsigned r = v.u + 0x7fffu + ((v.u >> 16) & 1u);
    return (unsigned short)(r >> 16);
}
__device__ __forceinline__ float bf2f(unsigned short h) {
    union { unsigned u; float f; } v; v.u = ((unsigned)h) << 16;
    return v.f;
}
__device__ __forceinline__ float gelu_tanh(float x) {
    float u = 0.7978845608028654f * (x + 0.044715f * x * x * x);
    float t = 1.0f - 2.0f / (__expf(2.0f * u) + 1.0f);
    return 0.5f * x * (1.0f + t);
}

// ---------------- utility ----------------
__global__ void k_zero(float* __restrict__ p, int n) {
    int i = blockIdx.x * 256 + threadIdx.x;
    if (i < n) p[i] = 0.f;
}
__global__ void k_fillz(float* __restrict__ p, int n) {
    int i = blockIdx.x * 256 + threadIdx.x;
    if (i < n) p[i] = 0.f;
}
__global__ void k_f32_to_bf16(const float* __restrict__ src, unsigned short* __restrict__ dst, int n) {
    int i = blockIdx.x * 256 + threadIdx.x;
    if (i < n) dst[i] = f2bf(src[i]);
}

// Combined qkv weight: Wc[tap][co][ci] = sum_k w2[co][k][tap] * w1[k][ci]
// w2: (288,288,3,3) fp32, w1: (288,96,1,1) fp32 -> out bf16 [9][288][96]
__global__ void k_combine_qkv(const float* __restrict__ w2, const float* __restrict__ w1,
        unsigned short* __restrict__ out) {
    int bx = blockIdx.x;           // 9*288
    int tap = bx / 288, co = bx % 288;
    int ci = threadIdx.x;          // 96
    const float* w2p = w2 + (size_t)co * 2592 + tap;
    float acc = 0.f;
    for (int k = 0; k < 288; k++)
        acc += w2p[k * 9] * w1[k * 96 + ci];
    out[((size_t)tap * 288 + co) * 96 + ci] = f2bf(acc);
}

// ---------------- LN1: NCHW fp32 -> xres (NHWC bf16) + y1 (NHWC bf16) ----------------
__global__ __launch_bounds__(256) void k_ln1(const float* __restrict__ x,
        const float* __restrict__ lnw, const float* __restrict__ lnb,
        unsigned short* __restrict__ xres, unsigned short* __restrict__ y1) {
    __shared__ float tile[96 * 65];
    __shared__ float smu[64], srs[64];
    const int t = threadIdx.x;
    const int p0 = blockIdx.x * 64;
    const int b = p0 >> 16, hw0 = p0 & 65535;
    #pragma unroll
    for (int i = 0; i < 24; i++) {
        int g = i * 256 + t;
        int c = g >> 6, pos = g & 63;
        tile[c * 65 + pos] = x[(size_t)(b * 96 + c) * 65536 + hw0 + pos];
    }
    __syncthreads();
    if (t < 64) {
        float s = 0.f, s2 = 0.f;
        for (int c = 0; c < 96; c++) { float v = tile[c * 65 + t]; s += v; s2 += v * v; }
        float mu = s * (1.0f / 96.0f);
        float var = s2 * (1.0f / 96.0f) - mu * mu;
        smu[t] = mu; srs[t] = rsqrtf(var + 1e-5f);
    }
    __syncthreads();
    #pragma unroll
    for (int i = 0; i < 12; i++) {
        int g2 = (i * 256 + t) * 2;
        int pos = g2 / 96, c = g2 % 96;
        float v0 = tile[c * 65 + pos], v1 = tile[(c + 1) * 65 + pos];
        float mu = smu[pos], rs = srs[pos];
        size_t o = (size_t)(p0 + pos) * 96 + c;
        *(unsigned*)(xres + o) = (unsigned)f2bf(v0) | ((unsigned)f2bf(v1) << 16);
        unsigned short a0 = f2bf((v0 - mu) * rs * lnw[c] + lnb[c]);
        unsigned short a1 = f2bf((v1 - mu) * rs * lnw[c + 1] + lnb[c + 1]);
        *(unsigned*)(y1 + o) = (unsigned)a0 | ((unsigned)a1 << 16);
    }
}

// ---------------- LN2: NHWC fp32 -> NHWC bf16 ----------------
__global__ __launch_bounds__(256) void k_ln2(const float* __restrict__ xin,
        const float* __restrict__ lnw, const float* __restrict__ lnb,
        unsigned short* __restrict__ y2) {
    __shared__ float tile[64 * 97];
    __shared__ float smu[64], srs[64];
    const int t = threadIdx.x;
    const int p0 = blockIdx.x * 64;
    #pragma unroll
    for (int i = 0; i < 24; i++) {
        int g = i * 256 + t;
        int pos = g / 96, c = g % 96;
        tile[pos * 97 + c] = xin[(size_t)p0 * 96 + g];
    }
    __syncthreads();
    if (t < 64) {
        float s = 0.f, s2 = 0.f;
        for (int c = 0; c < 96; c++) { float v = tile[t * 97 + c]; s += v; s2 += v * v; }
        float mu = s * (1.0f / 96.0f);
        float var = s2 * (1.0f / 96.0f) - mu * mu;
        smu[t] = mu; srs[t] = rsqrtf(var + 1e-5f);
    }
    __syncthreads();
    #pragma unroll
    for (int i = 0; i < 12; i++) {
        int g2 = (i * 256 + t) * 2;
        int pos = g2 / 96, c = g2 % 96;
        float mu = smu[pos], rs = srs[pos];
        unsigned short a0 = f2bf((tile[pos * 97 + c] - mu) * rs * lnw[c] + lnb[c]);
        unsigned short a1 = f2bf((tile[pos * 97 + c + 1] - mu) * rs * lnw[c + 1] + lnb[c + 1]);
        *(unsigned*)(y2 + (size_t)p0 * 96 + g2) = (unsigned)a0 | ((unsigned)a1 << 16);
    }
}

// ---------------- NHWC fp32 -> NCHW fp32 (final output) ----------------
__global__ __launch_bounds__(256) void k_tout(const float* __restrict__ xin, float* __restrict__ out) {
    __shared__ float tile[96 * 65];
    const int t = threadIdx.x;
    const int p0 = blockIdx.x * 64;
    const int b = p0 >> 16, hw0 = p0 & 65535;
    #pragma unroll
    for (int i = 0; i < 24; i++) {
        int g = i * 256 + t;
        int pos = g / 96, c = g % 96;
        tile[c * 65 + pos] = xin[(size_t)p0 * 96 + g];
    }
    __syncthreads();
    #pragma unroll
    for (int i = 0; i < 24; i++) {
        int g = i * 256 + t;
        int c = g >> 6, pos = g & 63;
        out[(size_t)(b * 96 + c) * 65536 + hw0 + pos] = tile[c * 65 + pos];
    }
}

// ---------------- MFMA GEMM: C[pos][co] = sum_k A[pos][k] * W[co][k] ----------------
// TAPS3: implicit 3x3 window, W is [tap][NOUT][K].
// EPI 0: OUT bf16 [NPOS][NOUT].
// EPI 1: OUT fp32 = RES(fp32) + acc   (NOUT==96, co0==0)
// EPI 2: OUT fp32 = RES(bf16) + acc   (NOUT==96, co0==0)
template<int K, int NOUT, bool TAPS3, int EPI>
__global__ __launch_bounds__(256, 2) void k_gemm(
        const unsigned short* __restrict__ A, const unsigned short* __restrict__ W,
        const void* __restrict__ RES, void* __restrict__ OUT) {
    constexpr int KC = 96;
    constexpr int LDA = KC + 8; // pad -> max 2-way LDS conflicts (free)
    static_assert(K % KC == 0, "K multiple of 96");
    __shared__ unsigned short As[128 * LDA];
    __shared__ unsigned short Bs[96 * LDA];

    const int t = threadIdx.x;
    const int wv = t >> 6, lane = t & 63;
    const int quad = lane >> 4, lrow = lane & 15;
    const int p0 = blockIdx.x * 128;
    const int co0 = blockIdx.y * 96;

    f32x4 acc[2][6];
    f32x4 zero = {0.f, 0.f, 0.f, 0.f};
    #pragma unroll
    for (int i = 0; i < 2; i++)
        #pragma unroll
        for (int j = 0; j < 6; j++) acc[i][j] = zero;

    const int ntap = TAPS3 ? 9 : 1;
    for (int tap = 0; tap < ntap; tap++) {
        int dy = 0, dx = 0;
        if (TAPS3) {
            dy = tap / 3 - 1; dx = tap % 3 - 1;
            int h = (p0 >> 8) & 255;               // uniform over block (128 | p0)
            if ((unsigned)(h + dy) >= 256u) continue;
        }
        for (int kc = 0; kc < K / KC; kc++) {
            const int k0 = kc * KC;
            // stage A: 128 rows x 96 k
            #pragma unroll
            for (int i = 0; i < 6; i++) {
                int g = i * 256 + t;
                int row = g / 12, u = g % 12;
                uint4 val = {0u, 0u, 0u, 0u};
                int p = p0 + row;
                bool ok = true;
                const unsigned short* src;
                if (TAPS3) {
                    int wc = p & 255;
                    ok = ((unsigned)(wc + dx) < 256u);
                    src = A + (size_t)(p + dy * 256 + dx) * K + k0 + u * 8;
                } else {
                    src = A + (size_t)p * K + k0 + u * 8;
                }
                if (ok) val = *(const uint4*)src;
                *(uint4*)(As + row * LDA + u * 8) = val;
            }
            // stage B: 96 rows x 96 k
            for (int g = t; g < 1152; g += 256) {
                int row = g / 12, u = g % 12;
                const unsigned short* src = W + ((size_t)tap * NOUT + co0 + row) * K + k0 + u * 8;
                *(uint4*)(Bs + row * LDA + u * 8) = *(const uint4*)src;
            }
            __syncthreads();
            #pragma unroll
            for (int kk = 0; kk < 3; kk++) {
                bf16x8 a[2], b[6];
                #pragma unroll
                for (int mt = 0; mt < 2; mt++)
                    a[mt] = *(const bf16x8*)(As + (wv * 32 + mt * 16 + lrow) * LDA + kk * 32 + quad * 8);
                #pragma unroll
                for (int nt = 0; nt < 6; nt++)
                    b[nt] = *(const bf16x8*)(Bs + (nt * 16 + lrow) * LDA + kk * 32 + quad * 8);
                #pragma unroll
                for (int mt = 0; mt < 2; mt++)
                    #pragma unroll
                    for (int nt = 0; nt < 6; nt++)
                        acc[mt][nt] = __builtin_amdgcn_mfma_f32_16x16x32_bf16(a[mt], b[nt], acc[mt][nt], 0, 0, 0);
            }
            __syncthreads();
        }
    }

    if (EPI == 0) {
        #pragma unroll
        for (int mt = 0; mt < 2; mt++)
            #pragma unroll
            for (int nt = 0; nt < 6; nt++)
                #pragma unroll
                for (int r = 0; r < 4; r++) {
                    int m = wv * 32 + mt * 16 + quad * 4 + r;
                    int n = nt * 16 + lrow;
                    As[m * LDA + n] = f2bf(acc[mt][nt][r]);
                }
        __syncthreads();
        unsigned short* o = (unsigned short*)OUT;
        #pragma unroll
        for (int i = 0; i < 6; i++) {
            int g = i * 256 + t;
            int row = g / 12, u = g % 12;
            *(uint4*)(o + (size_t)(p0 + row) * NOUT + co0 + u * 8) = *(const uint4*)(As + row * LDA + u * 8);
        }
    } else {
        float* o = (float*)OUT;
        #pragma unroll
        for (int mt = 0; mt < 2; mt++)
            #pragma unroll
            for (int nt = 0; nt < 6; nt++)
                #pragma unroll
                for (int r = 0; r < 4; r++) {
                    int m = wv * 32 + mt * 16 + quad * 4 + r;
                    int n = nt * 16 + lrow;
                    size_t idx = (size_t)(p0 + m) * NOUT + co0 + n;
                    float res = (EPI == 1) ? ((const float*)RES)[idx]
                                           : bf2f(((const unsigned short*)RES)[idx]);
                    o[idx] = res + acc[mt][nt][r];
                }
    }
}

// ---------------- attention stats: Gram (q.k^T) + channel sq-norms ----------------
__global__ __launch_bounds__(256) void k_attn_stats(const unsigned short* __restrict__ qkv,
        float* __restrict__ G, float* __restrict__ nrm) {
    __shared__ unsigned short tile[64 * 200];
    const int t = threadIdx.x;
    const int p0 = blockIdx.x * 256;
    const int b = p0 >> 16;
    const int cq = t >> 4, ck = t & 15;
    float gacc[6] = {0, 0, 0, 0, 0, 0};
    float nacc = 0.f;
    for (int tl = 0; tl < 4; tl++) {
        int pbase = p0 + tl * 64;
        #pragma unroll
        for (int i = 0; i < 6; i++) {
            int g = i * 256 + t;
            int row = g / 24, u = g % 24;
            *(uint4*)(tile + row * 200 + u * 8) = *(const uint4*)(qkv + (size_t)(pbase + row) * 288 + u * 8);
        }
        __syncthreads();
        #pragma unroll
        for (int hd = 0; hd < 6; hd++) {
            float a = 0.f;
            for (int p = 0; p < 64; p++) {
                float qv = bf2f(tile[p * 200 + hd * 16 + cq]);
                float kv = bf2f(tile[p * 200 + 96 + hd * 16 + ck]);
                a += qv * kv;
            }
            gacc[hd] += a;
        }
        if (t < 192) {
            float a = 0.f;
            for (int p = 0; p < 64; p++) { float v = bf2f(tile[p * 200 + t]); a += v * v; }
            nacc += a;
        }
        __syncthreads();
    }
    #pragma unroll
    for (int hd = 0; hd < 6; hd++)
        atomicAdd(&G[((b * 6 + hd) * 16 + cq) * 16 + ck], gacc[hd]);
    if (t < 192) atomicAdd(&nrm[b * 192 + t], nacc);
}

// ---------------- softmax over 16-wide rows (24 bh x 16 rows) ----------------
__global__ void k_softmax(const float* __restrict__ G, const float* __restrict__ nrm,
        const float* __restrict__ scale, float* __restrict__ attnW) {
    int t = threadIdx.x; // 384 threads
    int bh = t >> 4, cq = t & 15;
    int b = bh / 6, hd = bh % 6;
    float qn = fmaxf(sqrtf(nrm[b * 192 + hd * 16 + cq]), 1e-12f);
    float l[16];
    float mx = -1e30f;
    #pragma unroll
    for (int ck = 0; ck < 16; ck++) {
        float kn = fmaxf(sqrtf(nrm[b * 192 + 96 + hd * 16 + ck]), 1e-12f);
        float v = G[(bh * 16 + cq) * 16 + ck] / (qn * kn) * scale[hd];
        l[ck] = v; mx = fmaxf(mx, v);
    }
    float s = 0.f;
    #pragma unroll
    for (int ck = 0; ck < 16; ck++) { l[ck] = __expf(l[ck] - mx); s += l[ck]; }
    float inv = 1.f / s;
    #pragma unroll
    for (int ck = 0; ck < 16; ck++) attnW[(bh * 16 + cq) * 16 + ck] = l[ck] * inv;
}

// ---------------- apply attention ----------------
__global__ __launch_bounds__(256) void k_apply(const unsigned short* __restrict__ qkv,
        const float* __restrict__ attnW, unsigned short* __restrict__ out) {
    __shared__ float aw[1536];
    const int t = threadIdx.x;
    const int p0 = blockIdx.x * 256;
    const int b = p0 >> 16;
    for (int i = t; i < 1536; i += 256) aw[i] = attnW[b * 1536 + i];
    __syncthreads();
    const int p = p0 + t;
    const unsigned short* vp = qkv + (size_t)p * 288 + 192;
    float v[96];
    #pragma unroll
    for (int i = 0; i < 12; i++) {
        uint4 d = *(const uint4*)(vp + i * 8);
        unsigned arr[4] = {d.x, d.y, d.z, d.w};
        #pragma unroll
        for (int j = 0; j < 4; j++) {
            v[i * 8 + j * 2]     = bf2f((unsigned short)(arr[j] & 0xffffu));
            v[i * 8 + j * 2 + 1] = bf2f((unsigned short)(arr[j] >> 16));
        }
    }
    unsigned short* outp = out + (size_t)p * 96;
    #pragma unroll
    for (int i = 0; i < 12; i++) {
        unsigned pk[4];
        #pragma unroll
        for (int j = 0; j < 4; j++) {
            float o2[2];
            #pragma unroll
            for (int e = 0; e < 2; e++) {
                int ch = i * 8 + j * 2 + e;
                int hd = ch >> 4;
                float a = 0.f;
                #pragma unroll
                for (int ck = 0; ck < 16; ck++) a += aw[ch * 16 + ck] * v[hd * 16 + ck];
                o2[e] = a;
            }
            pk[j] = (unsigned)f2bf(o2[0]) | ((unsigned)f2bf(o2[1]) << 16);
        }
        uint4 d; d.x = pk[0]; d.y = pk[1]; d.z = pk[2]; d.w = pk[3];
        *(uint4*)(outp + i * 8) = d;
    }
}

// ---------------- grouped 3x3 dwconv (2ch/group) + gelu gate ----------------
__global__ __launch_bounds__(192) void k_dwgate(const unsigned short* __restrict__ h1,
        const float* __restrict__ dww, unsigned short* __restrict__ out) {
    __shared__ float wl[18 * 384];
    const int t = threadIdx.x; // 192
    for (int g = t; g < 6912; g += 192) {
        int tap = g % 9, j = (g / 9) % 2, o = g / 18;
        wl[(tap * 2 + j) * 384 + o] = dww[g];
    }
    __syncthreads();
    const int c2 = t % 96, psub = t / 96;
    const int p0 = blockIdx.x * 32;
    for (int it = 0; it < 16; it++) {
        int p = p0 + psub + it * 2;
        int h = (p >> 8) & 255, w = p & 255;
        float a0 = 0, a1 = 0, a2 = 0, a3 = 0;
        #pragma unroll
        for (int tap = 0; tap < 9; tap++) {
            int dy = tap / 3 - 1, dx = tap % 3 - 1;
            if ((unsigned)(h + dy) >= 256u || (unsigned)(w + dx) >= 256u) continue;
            int pp = p + dy * 256 + dx;
            unsigned d1 = *(const unsigned*)(h1 + (size_t)pp * 384 + 2 * c2);
            unsigned d2 = *(const unsigned*)(h1 + (size_t)pp * 384 + 192 + 2 * c2);
            float i0 = bf2f((unsigned short)(d1 & 0xffffu)), i1 = bf2f((unsigned short)(d1 >> 16));
            float i2 = bf2f((unsigned short)(d2 & 0xffffu)), i3 = bf2f((unsigned short)(d2 >> 16));
            const float* wb = wl + tap * 768;
            a0 += wb[2 * c2] * i0           + wb[384 + 2 * c2] * i1;
            a1 += wb[2 * c2 + 1] * i0       + wb[384 + 2 * c2 + 1] * i1;
            a2 += wb[192 + 2 * c2] * i2     + wb[384 + 192 + 2 * c2] * i3;
            a3 += wb[192 + 2 * c2 + 1] * i2 + wb[384 + 192 + 2 * c2 + 1] * i3;
        }
        float g0 = gelu_tanh(a0) * a2;
        float g1 = gelu_tanh(a1) * a3;
        unsigned pack = (unsigned)f2bf(g0) | ((unsigned)f2bf(g1) << 16);
        *(unsigned*)(out + (size_t)p * 192 + 2 * c2) = pack;
    }
}

extern "C" void kernel_launch(void* const* d_in, const int* in_sizes, int n_in,
                              void* d_out, int out_size, void* d_ws, size_t ws_size,
                              hipStream_t stream) {
    const float* x      = (const float*)d_in[0];
    const float* ln1_w  = (const float*)d_in[1];
    const float* ln1_b  = (const float*)d_in[2];
    const float* qkv1_w = (const float*)d_in[3];
    const float* qkv2_w = (const float*)d_in[4];
    const float* proj_w = (const float*)d_in[5];
    const float* scale  = (const float*)d_in[6];
    const float* ln2_w  = (const float*)d_in[7];
    const float* ln2_b  = (const float*)d_in[8];
    const float* pin_w  = (const float*)d_in[9];
    const float* dw_w   = (const float*)d_in[10];
    const float* pout_w = (const float*)d_in[11];
    float* out = (float*)d_out;

    // ---- arena (explicit offsets, total ~289 MB) ----
    constexpr size_t SZ_WCOMB = (size_t)9 * 288 * 96 * 2;      //   497,664
    constexpr size_t SZ_WPROJ = (size_t)96 * 96 * 2;           //    18,432
    constexpr size_t SZ_WPIN  = (size_t)384 * 96 * 2;          //    73,728
    constexpr size_t SZ_WPOUT = (size_t)96 * 192 * 2;          //    36,864
    constexpr size_t SZ_STATS = (size_t)13056 * 4;             //    52,224 (G 6144f | nrm 768f | attnW 6144f)
    constexpr size_t SZ_A = (size_t)NPOS * 96 * 2;             // 48 MB
    constexpr size_t SZ_B = (size_t)NPOS * 288 * 2;            // 144 MB
    constexpr size_t SZ_C = (size_t)NPOS * 96 * 4;             // 96 MB
    constexpr size_t OFF_WCOMB = 0;
    constexpr size_t OFF_WPROJ = OFF_WCOMB + SZ_WCOMB;
    constexpr size_t OFF_WPIN  = OFF_WPROJ + SZ_WPROJ;
    constexpr size_t OFF_WPOUT = OFF_WPIN + SZ_WPIN;
    constexpr size_t OFF_STATS = OFF_WPOUT + SZ_WPOUT;
    constexpr size_t OFF_A = OFF_STATS + SZ_STATS;             //   678,912
    constexpr size_t OFF_B = OFF_A + SZ_A;
    constexpr size_t OFF_C = OFF_B + SZ_B;
    constexpr size_t NEED = OFF_C + SZ_C;                      // ~302.7 MB

    if (ws_size < NEED) {
        // workspace too small: emit zeros (clean numeric failure as diagnostic)
        k_fillz<<<(out_size + 255) / 256, 256, 0, stream>>>(out, out_size);
        return;
    }

    char* ws = (char*)d_ws;
    unsigned short* Wcomb = (unsigned short*)(ws + OFF_WCOMB);
    unsigned short* Wproj = (unsigned short*)(ws + OFF_WPROJ);
    unsigned short* Wpin  = (unsigned short*)(ws + OFF_WPIN);
    unsigned short* Wpout = (unsigned short*)(ws + OFF_WPOUT);
    float* stats = (float*)(ws + OFF_STATS);
    float* G     = stats;
    float* nrm   = stats + 6144;
    float* attnW = stats + 6912;

    unsigned short* y1       = (unsigned short*)(ws + OFF_A);  // LN1 -> qkvconv
    unsigned short* attn_out = (unsigned short*)(ws + OFF_A);  // apply -> proj (y1 dead)
    unsigned short* qkv      = (unsigned short*)(ws + OFF_B);  // qkvconv -> stats/apply
    unsigned short* xres     = (unsigned short*)(ws + OFF_C);  // LN1 -> proj epi (48 MB)
    unsigned short* y2       = (unsigned short*)(ws + OFF_C + SZ_A); // LN2 -> pin (48 MB)
    unsigned short* h1       = (unsigned short*)(ws + OFF_A);  // pin -> dwgate (192 MB over A|B)
    unsigned short* gated    = (unsigned short*)(ws + OFF_C);  // dwgate -> pout (96 MB over C)
    float*          Fout     = (float*)(ws + OFF_A);           // pout -> tout (96 MB over A|B)
    float* x2 = out;                                           // NHWC fp32 residual in d_out

    // weight prep
    k_combine_qkv<<<9 * 288, 96, 0, stream>>>(qkv2_w, qkv1_w, Wcomb);
    k_f32_to_bf16<<<(96 * 96 + 255) / 256, 256, 0, stream>>>(proj_w, Wproj, 96 * 96);
    k_f32_to_bf16<<<(384 * 96 + 255) / 256, 256, 0, stream>>>(pin_w, Wpin, 384 * 96);
    k_f32_to_bf16<<<(96 * 192 + 255) / 256, 256, 0, stream>>>(pout_w, Wpout, 96 * 192);
    k_zero<<<(6912 + 255) / 256, 256, 0, stream>>>(stats, 6912);  // G + nrm

    // LN1 (+ NCHW->NHWC), residual snapshot
    k_ln1<<<NPOS / 64, 256, 0, stream>>>(x, ln1_w, ln1_b, xres, y1);
    // combined qkv conv: 3x3, 96 -> 288
    k_gemm<96, 288, true, 0><<<dim3(2048, 3), 256, 0, stream>>>(y1, Wcomb, nullptr, qkv);
    // attention
    k_attn_stats<<<NPOS / 256, 256, 0, stream>>>(qkv, G, nrm);
    k_softmax<<<1, 384, 0, stream>>>(G, nrm, scale, attnW);
    k_apply<<<NPOS / 256, 256, 0, stream>>>(qkv, attnW, attn_out);
    // proj + residual(bf16) -> x2 (NHWC fp32 in d_out)
    k_gemm<96, 96, false, 2><<<dim3(2048, 1), 256, 0, stream>>>(attn_out, Wproj, xres, x2);
    // LN2
    k_ln2<<<NPOS / 64, 256, 0, stream>>>(x2, ln2_w, ln2_b, y2);
    // pin: 96 -> 384
    k_gemm<96, 384, false, 0><<<dim3(2048, 4), 256, 0, stream>>>(y2, Wpin, nullptr, h1);
    // grouped 3x3 + gelu gate -> gated [NPOS][192]
    k_dwgate<<<NPOS / 32, 192, 0, stream>>>(h1, dw_w, gated);
    // pout + residual(fp32 x2) -> Fout
    k_gemm<192, 96, false, 1><<<dim3(2048, 1), 256, 0, stream>>>(gated, Wpout, x2, Fout);
    // NHWC -> NCHW final
    k_tout<<<NPOS / 64, 256, 0, stream>>>(Fout, out);
}

// Round 3
// 1326.273 us; speedup vs baseline: 1.9645x; 1.9645x over previous
//
#include <hip/hip_runtime.h>
#include <hip/hip_bf16.h>

#define NPOS 262144   // 4 * 256 * 256

typedef short bf16x8 __attribute__((ext_vector_type(8)));
typedef float f32x4 __attribute__((ext_vector_type(4)));

__device__ __forceinline__ unsigned short f2bf(float f) {
    union { float f; unsigned u; } v; v.f = f;
    unsigned r = v.u + 0x7fffu + ((v.u >> 16) & 1u);
    return (unsigned short)(r >> 16);
}
__device__ __forceinline__ float bf2f(unsigned short h) {
    union { unsigned u; float f; } v; v.u = ((unsigned)h) << 16;
    return v.f;
}
__device__ __forceinline__ float gelu_tanh(float x) {
    float u = 0.7978845608028654f * (x + 0.044715f * x * x * x);
    float t = 1.0f - 2.0f / (__expf(2.0f * u) + 1.0f);
    return 0.5f * x * (1.0f + t);
}

// ---------------- utility ----------------
__global__ void k_fillz(float* __restrict__ p, int n) {
    int i = blockIdx.x * 256 + threadIdx.x;
    if (i < n) p[i] = 0.f;
}
__global__ void k_f32_to_bf16(const float* __restrict__ src, unsigned short* __restrict__ dst, int n) {
    int i = blockIdx.x * 256 + threadIdx.x;
    if (i < n) dst[i] = f2bf(src[i]);
}

// Combined qkv weight: Wc[tap][co][ci] = sum_k w2[co][k][tap] * w1[k][ci]
__global__ void k_combine_qkv(const float* __restrict__ w2, const float* __restrict__ w1,
        unsigned short* __restrict__ out) {
    int bx = blockIdx.x;           // 9*288
    int tap = bx / 288, co = bx % 288;
    int ci = threadIdx.x;          // 96
    const float* w2p = w2 + (size_t)co * 2592 + tap;
    float acc = 0.f;
    for (int k = 0; k < 288; k++)
        acc += w2p[k * 9] * w1[k * 96 + ci];
    out[((size_t)tap * 288 + co) * 96 + ci] = f2bf(acc);
}

// ---------------- LN1: NCHW fp32 -> xres (NHWC bf16) + y1 (NHWC bf16) ----------------
__global__ __launch_bounds__(256) void k_ln1(const float* __restrict__ x,
        const float* __restrict__ lnw, const float* __restrict__ lnb,
        unsigned short* __restrict__ xres, unsigned short* __restrict__ y1) {
    __shared__ float tile[96 * 65];
    __shared__ float smu[64], srs[64];
    const int t = threadIdx.x;
    const int p0 = blockIdx.x * 64;
    const int b = p0 >> 16, hw0 = p0 & 65535;
    #pragma unroll
    for (int i = 0; i < 24; i++) {
        int g = i * 256 + t;
        int c = g >> 6, pos = g & 63;
        tile[c * 65 + pos] = x[(size_t)(b * 96 + c) * 65536 + hw0 + pos];
    }
    __syncthreads();
    if (t < 64) {
        float s = 0.f, s2 = 0.f;
        for (int c = 0; c < 96; c++) { float v = tile[c * 65 + t]; s += v; s2 += v * v; }
        float mu = s * (1.0f / 96.0f);
        float var = s2 * (1.0f / 96.0f) - mu * mu;
        smu[t] = mu; srs[t] = rsqrtf(var + 1e-5f);
    }
    __syncthreads();
    #pragma unroll
    for (int i = 0; i < 12; i++) {
        int g2 = (i * 256 + t) * 2;
        int pos = g2 / 96, c = g2 % 96;
        float v0 = tile[c * 65 + pos], v1 = tile[(c + 1) * 65 + pos];
        float mu = smu[pos], rs = srs[pos];
        size_t o = (size_t)(p0 + pos) * 96 + c;
        *(unsigned*)(xres + o) = (unsigned)f2bf(v0) | ((unsigned)f2bf(v1) << 16);
        unsigned short a0 = f2bf((v0 - mu) * rs * lnw[c] + lnb[c]);
        unsigned short a1 = f2bf((v1 - mu) * rs * lnw[c + 1] + lnb[c + 1]);
        *(unsigned*)(y1 + o) = (unsigned)a0 | ((unsigned)a1 << 16);
    }
}

// ---------------- LN2: NHWC fp32 -> NHWC bf16 ----------------
__global__ __launch_bounds__(256) void k_ln2(const float* __restrict__ xin,
        const float* __restrict__ lnw, const float* __restrict__ lnb,
        unsigned short* __restrict__ y2) {
    __shared__ float tile[64 * 97];
    __shared__ float smu[64], srs[64];
    const int t = threadIdx.x;
    const int p0 = blockIdx.x * 64;
    #pragma unroll
    for (int i = 0; i < 24; i++) {
        int g = i * 256 + t;
        int pos = g / 96, c = g % 96;
        tile[pos * 97 + c] = xin[(size_t)p0 * 96 + g];
    }
    __syncthreads();
    if (t < 64) {
        float s = 0.f, s2 = 0.f;
        for (int c = 0; c < 96; c++) { float v = tile[t * 97 + c]; s += v; s2 += v * v; }
        float mu = s * (1.0f / 96.0f);
        float var = s2 * (1.0f / 96.0f) - mu * mu;
        smu[t] = mu; srs[t] = rsqrtf(var + 1e-5f);
    }
    __syncthreads();
    #pragma unroll
    for (int i = 0; i < 12; i++) {
        int g2 = (i * 256 + t) * 2;
        int pos = g2 / 96, c = g2 % 96;
        float mu = smu[pos], rs = srs[pos];
        unsigned short a0 = f2bf((tile[pos * 97 + c] - mu) * rs * lnw[c] + lnb[c]);
        unsigned short a1 = f2bf((tile[pos * 97 + c + 1] - mu) * rs * lnw[c + 1] + lnb[c + 1]);
        *(unsigned*)(y2 + (size_t)p0 * 96 + g2) = (unsigned)a0 | ((unsigned)a1 << 16);
    }
}

// ---------------- NHWC fp32 -> NCHW fp32 (final output) ----------------
__global__ __launch_bounds__(256) void k_tout(const float* __restrict__ xin, float* __restrict__ out) {
    __shared__ float tile[96 * 65];
    const int t = threadIdx.x;
    const int p0 = blockIdx.x * 64;
    const int b = p0 >> 16, hw0 = p0 & 65535;
    #pragma unroll
    for (int i = 0; i < 24; i++) {
        int g = i * 256 + t;
        int pos = g / 96, c = g % 96;
        tile[c * 65 + pos] = xin[(size_t)p0 * 96 + g];
    }
    __syncthreads();
    #pragma unroll
    for (int i = 0; i < 24; i++) {
        int g = i * 256 + t;
        int c = g >> 6, pos = g & 63;
        out[(size_t)(b * 96 + c) * 65536 + hw0 + pos] = tile[c * 65 + pos];
    }
}

// ---------------- MFMA GEMM: C[pos][co] = sum_k A[pos][k] * W[co][k] ----------------
template<int K, int NOUT, bool TAPS3, int EPI>
__global__ __launch_bounds__(256, 2) void k_gemm(
        const unsigned short* __restrict__ A, const unsigned short* __restrict__ W,
        const void* __restrict__ RES, void* __restrict__ OUT) {
    constexpr int KC = 96;
    constexpr int LDA = KC + 8;
    static_assert(K % KC == 0, "K multiple of 96");
    __shared__ unsigned short As[128 * LDA];
    __shared__ unsigned short Bs[96 * LDA];

    const int t = threadIdx.x;
    const int wv = t >> 6, lane = t & 63;
    const int quad = lane >> 4, lrow = lane & 15;
    const int p0 = blockIdx.x * 128;
    const int co0 = blockIdx.y * 96;

    f32x4 acc[2][6];
    f32x4 zero = {0.f, 0.f, 0.f, 0.f};
    #pragma unroll
    for (int i = 0; i < 2; i++)
        #pragma unroll
        for (int j = 0; j < 6; j++) acc[i][j] = zero;

    const int ntap = TAPS3 ? 9 : 1;
    for (int tap = 0; tap < ntap; tap++) {
        int dy = 0, dx = 0;
        if (TAPS3) {
            dy = tap / 3 - 1; dx = tap % 3 - 1;
            int h = (p0 >> 8) & 255;
            if ((unsigned)(h + dy) >= 256u) continue;
        }
        for (int kc = 0; kc < K / KC; kc++) {
            const int k0 = kc * KC;
            #pragma unroll
            for (int i = 0; i < 6; i++) {
                int g = i * 256 + t;
                int row = g / 12, u = g % 12;
                uint4 val = {0u, 0u, 0u, 0u};
                int p = p0 + row;
                bool ok = true;
                const unsigned short* src;
                if (TAPS3) {
                    int wc = p & 255;
                    ok = ((unsigned)(wc + dx) < 256u);
                    src = A + (size_t)(p + dy * 256 + dx) * K + k0 + u * 8;
                } else {
                    src = A + (size_t)p * K + k0 + u * 8;
                }
                if (ok) val = *(const uint4*)src;
                *(uint4*)(As + row * LDA + u * 8) = val;
            }
            for (int g = t; g < 1152; g += 256) {
                int row = g / 12, u = g % 12;
                const unsigned short* src = W + ((size_t)tap * NOUT + co0 + row) * K + k0 + u * 8;
                *(uint4*)(Bs + row * LDA + u * 8) = *(const uint4*)src;
            }
            __syncthreads();
            #pragma unroll
            for (int kk = 0; kk < 3; kk++) {
                bf16x8 a[2], b[6];
                #pragma unroll
                for (int mt = 0; mt < 2; mt++)
                    a[mt] = *(const bf16x8*)(As + (wv * 32 + mt * 16 + lrow) * LDA + kk * 32 + quad * 8);
                #pragma unroll
                for (int nt = 0; nt < 6; nt++)
                    b[nt] = *(const bf16x8*)(Bs + (nt * 16 + lrow) * LDA + kk * 32 + quad * 8);
                #pragma unroll
                for (int mt = 0; mt < 2; mt++)
                    #pragma unroll
                    for (int nt = 0; nt < 6; nt++)
                        acc[mt][nt] = __builtin_amdgcn_mfma_f32_16x16x32_bf16(a[mt], b[nt], acc[mt][nt], 0, 0, 0);
            }
            __syncthreads();
        }
    }

    if (EPI == 0) {
        #pragma unroll
        for (int mt = 0; mt < 2; mt++)
            #pragma unroll
            for (int nt = 0; nt < 6; nt++)
                #pragma unroll
                for (int r = 0; r < 4; r++) {
                    int m = wv * 32 + mt * 16 + quad * 4 + r;
                    int n = nt * 16 + lrow;
                    As[m * LDA + n] = f2bf(acc[mt][nt][r]);
                }
        __syncthreads();
        unsigned short* o = (unsigned short*)OUT;
        #pragma unroll
        for (int i = 0; i < 6; i++) {
            int g = i * 256 + t;
            int row = g / 12, u = g % 12;
            *(uint4*)(o + (size_t)(p0 + row) * NOUT + co0 + u * 8) = *(const uint4*)(As + row * LDA + u * 8);
        }
    } else {
        float* o = (float*)OUT;
        #pragma unroll
        for (int mt = 0; mt < 2; mt++)
            #pragma unroll
            for (int nt = 0; nt < 6; nt++)
                #pragma unroll
                for (int r = 0; r < 4; r++) {
                    int m = wv * 32 + mt * 16 + quad * 4 + r;
                    int n = nt * 16 + lrow;
                    size_t idx = (size_t)(p0 + m) * NOUT + co0 + n;
                    float res = (EPI == 1) ? ((const float*)RES)[idx]
                                           : bf2f(((const unsigned short*)RES)[idx]);
                    o[idx] = res + acc[mt][nt][r];
                }
    }
}

// ---------------- attention stats: per-block partial Gram + sq-norms (NO atomics) ----------------
// LDS tile transposed: tt[ch][row] so the dot over positions reads contiguous ushort4.
__global__ __launch_bounds__(256) void k_attn_stats(const unsigned short* __restrict__ qkv,
        float* __restrict__ Gpart) {
    __shared__ unsigned short tt[192 * 68];
    const int t = threadIdx.x;
    const int bi = blockIdx.x;
    const int p0 = bi * 256;
    const int cq = t >> 4, ck = t & 15;
    float gacc[6] = {0, 0, 0, 0, 0, 0};
    float nacc = 0.f;
    for (int tl = 0; tl < 4; tl++) {
        const int pb = p0 + tl * 64;
        __syncthreads();
        // stage: wave-uniform channel-group u, row = lane -> conflict-free u16 writes
        #pragma unroll
        for (int i = 0; i < 6; i++) {
            int g = i * 256 + t;
            int u = g >> 6, row = g & 63;
            uint4 d = *(const uint4*)(qkv + (size_t)(pb + row) * 288 + u * 8);
            unsigned short v[8];
            *(uint4*)v = d;
            #pragma unroll
            for (int j = 0; j < 8; j++)
                tt[(u * 8 + j) * 68 + row] = v[j];
        }
        __syncthreads();
        #pragma unroll
        for (int hd = 0; hd < 6; hd++) {
            const unsigned short* qp = tt + (hd * 16 + cq) * 68;
            const unsigned short* kp = tt + (96 + hd * 16 + ck) * 68;
            float a = 0.f;
            #pragma unroll
            for (int pg = 0; pg < 16; pg++) {
                ushort4 q4 = *(const ushort4*)(qp + pg * 4);
                ushort4 k4 = *(const ushort4*)(kp + pg * 4);
                a += bf2f(q4.x) * bf2f(k4.x) + bf2f(q4.y) * bf2f(k4.y)
                   + bf2f(q4.z) * bf2f(k4.z) + bf2f(q4.w) * bf2f(k4.w);
            }
            gacc[hd] += a;
        }
        if (t < 192) {
            const unsigned short* cp = tt + t * 68;
            float a = 0.f;
            #pragma unroll
            for (int pg = 0; pg < 16; pg++) {
                ushort4 c4 = *(const ushort4*)(cp + pg * 4);
                a += bf2f(c4.x) * bf2f(c4.x) + bf2f(c4.y) * bf2f(c4.y)
                   + bf2f(c4.z) * bf2f(c4.z) + bf2f(c4.w) * bf2f(c4.w);
            }
            nacc += a;
        }
    }
    float* gp = Gpart + (size_t)bi * 1728;
    #pragma unroll
    for (int hd = 0; hd < 6; hd++) gp[hd * 256 + t] = gacc[hd];
    if (t < 192) gp[1536 + t] = nacc;
}

// Reduce 256 block-partials per image -> G[b*1536 + j], nrm[b*192 + j']
__global__ __launch_bounds__(256) void k_attn_reduce(const float* __restrict__ Gpart,
        float* __restrict__ G, float* __restrict__ nrm) {
    int idx = blockIdx.x * 256 + threadIdx.x;   // 0..6911
    int b = idx / 1728, j = idx % 1728;
    const float* src = Gpart + (size_t)(b * 256) * 1728 + j;
    float s = 0.f;
    for (int blk = 0; blk < 256; blk++) s += src[(size_t)blk * 1728];
    if (j < 1536) G[b * 1536 + j] = s;
    else nrm[b * 192 + (j - 1536)] = s;
}

// ---------------- softmax over 16-wide rows (24 bh x 16 rows) ----------------
__global__ void k_softmax(const float* __restrict__ G, const float* __restrict__ nrm,
        const float* __restrict__ scale, float* __restrict__ attnW) {
    int t = threadIdx.x; // 384 threads
    int bh = t >> 4, cq = t & 15;
    int b = bh / 6, hd = bh % 6;
    float qn = fmaxf(sqrtf(nrm[b * 192 + hd * 16 + cq]), 1e-12f);
    float l[16];
    float mx = -1e30f;
    #pragma unroll
    for (int ck = 0; ck < 16; ck++) {
        float kn = fmaxf(sqrtf(nrm[b * 192 + 96 + hd * 16 + ck]), 1e-12f);
        float v = G[(bh * 16 + cq) * 16 + ck] / (qn * kn) * scale[hd];
        l[ck] = v; mx = fmaxf(mx, v);
    }
    float s = 0.f;
    #pragma unroll
    for (int ck = 0; ck < 16; ck++) { l[ck] = __expf(l[ck] - mx); s += l[ck]; }
    float inv = 1.f / s;
    #pragma unroll
    for (int ck = 0; ck < 16; ck++) attnW[(bh * 16 + cq) * 16 + ck] = l[ck] * inv;
}

// ---------------- apply attention ----------------
__global__ __launch_bounds__(256) void k_apply(const unsigned short* __restrict__ qkv,
        const float* __restrict__ attnW, unsigned short* __restrict__ out) {
    __shared__ float aw[1536];
    const int t = threadIdx.x;
    const int p0 = blockIdx.x * 256;
    const int b = p0 >> 16;
    for (int i = t; i < 1536; i += 256) aw[i] = attnW[b * 1536 + i];
    __syncthreads();
    const int p = p0 + t;
    const unsigned short* vp = qkv + (size_t)p * 288 + 192;
    float v[96];
    #pragma unroll
    for (int i = 0; i < 12; i++) {
        uint4 d = *(const uint4*)(vp + i * 8);
        unsigned arr[4] = {d.x, d.y, d.z, d.w};
        #pragma unroll
        for (int j = 0; j < 4; j++) {
            v[i * 8 + j * 2]     = bf2f((unsigned short)(arr[j] & 0xffffu));
            v[i * 8 + j * 2 + 1] = bf2f((unsigned short)(arr[j] >> 16));
        }
    }
    unsigned short* outp = out + (size_t)p * 96;
    #pragma unroll
    for (int i = 0; i < 12; i++) {
        unsigned pk[4];
        #pragma unroll
        for (int j = 0; j < 4; j++) {
            float o2[2];
            #pragma unroll
            for (int e = 0; e < 2; e++) {
                int ch = i * 8 + j * 2 + e;
                int hd = ch >> 4;
                float a = 0.f;
                #pragma unroll
                for (int ck = 0; ck < 16; ck++) a += aw[ch * 16 + ck] * v[hd * 16 + ck];
                o2[e] = a;
            }
            pk[j] = (unsigned)f2bf(o2[0]) | ((unsigned)f2bf(o2[1]) << 16);
        }
        uint4 d; d.x = pk[0]; d.y = pk[1]; d.z = pk[2]; d.w = pk[3];
        *(uint4*)(outp + i * 8) = d;
    }
}

// ---------------- grouped 3x3 dwconv (2ch/group) + gelu gate ----------------
__global__ __launch_bounds__(192) void k_dwgate(const unsigned short* __restrict__ h1,
        const float* __restrict__ dww, unsigned short* __restrict__ out) {
    __shared__ float wl[18 * 384];
    const int t = threadIdx.x; // 192
    for (int g = t; g < 6912; g += 192) {
        int tap = g % 9, j = (g / 9) % 2, o = g / 18;
        wl[(tap * 2 + j) * 384 + o] = dww[g];
    }
    __syncthreads();
    const int c2 = t % 96, psub = t / 96;
    const int p0 = blockIdx.x * 32;
    for (int it = 0; it < 16; it++) {
        int p = p0 + psub + it * 2;
        int h = (p >> 8) & 255, w = p & 255;
        float a0 = 0, a1 = 0, a2 = 0, a3 = 0;
        #pragma unroll
        for (int tap = 0; tap < 9; tap++) {
            int dy = tap / 3 - 1, dx = tap % 3 - 1;
            if ((unsigned)(h + dy) >= 256u || (unsigned)(w + dx) >= 256u) continue;
            int pp = p + dy * 256 + dx;
            unsigned d1 = *(const unsigned*)(h1 + (size_t)pp * 384 + 2 * c2);
            unsigned d2 = *(const unsigned*)(h1 + (size_t)pp * 384 + 192 + 2 * c2);
            float i0 = bf2f((unsigned short)(d1 & 0xffffu)), i1 = bf2f((unsigned short)(d1 >> 16));
            float i2 = bf2f((unsigned short)(d2 & 0xffffu)), i3 = bf2f((unsigned short)(d2 >> 16));
            const float* wb = wl + tap * 768;
            a0 += wb[2 * c2] * i0           + wb[384 + 2 * c2] * i1;
            a1 += wb[2 * c2 + 1] * i0       + wb[384 + 2 * c2 + 1] * i1;
            a2 += wb[192 + 2 * c2] * i2     + wb[384 + 192 + 2 * c2] * i3;
            a3 += wb[192 + 2 * c2 + 1] * i2 + wb[384 + 192 + 2 * c2 + 1] * i3;
        }
        float g0 = gelu_tanh(a0) * a2;
        float g1 = gelu_tanh(a1) * a3;
        unsigned pack = (unsigned)f2bf(g0) | ((unsigned)f2bf(g1) << 16);
        *(unsigned*)(out + (size_t)p * 192 + 2 * c2) = pack;
    }
}

extern "C" void kernel_launch(void* const* d_in, const int* in_sizes, int n_in,
                              void* d_out, int out_size, void* d_ws, size_t ws_size,
                              hipStream_t stream) {
    const float* x      = (const float*)d_in[0];
    const float* ln1_w  = (const float*)d_in[1];
    const float* ln1_b  = (const float*)d_in[2];
    const float* qkv1_w = (const float*)d_in[3];
    const float* qkv2_w = (const float*)d_in[4];
    const float* proj_w = (const float*)d_in[5];
    const float* scale  = (const float*)d_in[6];
    const float* ln2_w  = (const float*)d_in[7];
    const float* ln2_b  = (const float*)d_in[8];
    const float* pin_w  = (const float*)d_in[9];
    const float* dw_w   = (const float*)d_in[10];
    const float* pout_w = (const float*)d_in[11];
    float* out = (float*)d_out;

    constexpr size_t SZ_WCOMB = (size_t)9 * 288 * 96 * 2;
    constexpr size_t SZ_WPROJ = (size_t)96 * 96 * 2;
    constexpr size_t SZ_WPIN  = (size_t)384 * 96 * 2;
    constexpr size_t SZ_WPOUT = (size_t)96 * 192 * 2;
    constexpr size_t SZ_STATS = (size_t)13056 * 4;
    constexpr size_t SZ_A = (size_t)NPOS * 96 * 2;             // 48 MB
    constexpr size_t SZ_B = (size_t)NPOS * 288 * 2;            // 144 MB
    constexpr size_t SZ_C = (size_t)NPOS * 96 * 4;             // 96 MB
    constexpr size_t OFF_WCOMB = 0;
    constexpr size_t OFF_WPROJ = OFF_WCOMB + SZ_WCOMB;
    constexpr size_t OFF_WPIN  = OFF_WPROJ + SZ_WPROJ;
    constexpr size_t OFF_WPOUT = OFF_WPIN + SZ_WPIN;
    constexpr size_t OFF_STATS = OFF_WPOUT + SZ_WPOUT;
    constexpr size_t OFF_A = OFF_STATS + SZ_STATS;
    constexpr size_t OFF_B = OFF_A + SZ_A;
    constexpr size_t OFF_C = OFF_B + SZ_B;
    constexpr size_t NEED = OFF_C + SZ_C;

    if (ws_size < NEED) {
        k_fillz<<<(out_size + 255) / 256, 256, 0, stream>>>(out, out_size);
        return;
    }

    char* ws = (char*)d_ws;
    unsigned short* Wcomb = (unsigned short*)(ws + OFF_WCOMB);
    unsigned short* Wproj = (unsigned short*)(ws + OFF_WPROJ);
    unsigned short* Wpin  = (unsigned short*)(ws + OFF_WPIN);
    unsigned short* Wpout = (unsigned short*)(ws + OFF_WPOUT);
    float* stats = (float*)(ws + OFF_STATS);
    float* G     = stats;
    float* nrm   = stats + 6144;
    float* attnW = stats + 6912;

    unsigned short* y1       = (unsigned short*)(ws + OFF_A);
    unsigned short* attn_out = (unsigned short*)(ws + OFF_A);
    unsigned short* qkv      = (unsigned short*)(ws + OFF_B);
    unsigned short* xres     = (unsigned short*)(ws + OFF_C);
    unsigned short* y2       = (unsigned short*)(ws + OFF_C + SZ_A);
    float*          Gpart    = (float*)(ws + OFF_C + SZ_A);    // 7.1 MB in y2's (dead) slot
    unsigned short* h1       = (unsigned short*)(ws + OFF_A);
    unsigned short* gated    = (unsigned short*)(ws + OFF_C);
    float*          Fout     = (float*)(ws + OFF_A);
    float* x2 = out;

    // weight prep
    k_combine_qkv<<<9 * 288, 96, 0, stream>>>(qkv2_w, qkv1_w, Wcomb);
    k_f32_to_bf16<<<(96 * 96 + 255) / 256, 256, 0, stream>>>(proj_w, Wproj, 96 * 96);
    k_f32_to_bf16<<<(384 * 96 + 255) / 256, 256, 0, stream>>>(pin_w, Wpin, 384 * 96);
    k_f32_to_bf16<<<(96 * 192 + 255) / 256, 256, 0, stream>>>(pout_w, Wpout, 96 * 192);

    // LN1 (+ NCHW->NHWC), residual snapshot
    k_ln1<<<NPOS / 64, 256, 0, stream>>>(x, ln1_w, ln1_b, xres, y1);
    // combined qkv conv: 3x3, 96 -> 288
    k_gemm<96, 288, true, 0><<<dim3(2048, 3), 256, 0, stream>>>(y1, Wcomb, nullptr, qkv);
    // attention (partials -> reduce -> softmax)
    k_attn_stats<<<NPOS / 256, 256, 0, stream>>>(qkv, Gpart);
    k_attn_reduce<<<27, 256, 0, stream>>>(Gpart, G, nrm);
    k_softmax<<<1, 384, 0, stream>>>(G, nrm, scale, attnW);
    k_apply<<<NPOS / 256, 256, 0, stream>>>(qkv, attnW, attn_out);
    // proj + residual(bf16) -> x2 (NHWC fp32 in d_out)
    k_gemm<96, 96, false, 2><<<dim3(2048, 1), 256, 0, stream>>>(attn_out, Wproj, xres, x2);
    // LN2
    k_ln2<<<NPOS / 64, 256, 0, stream>>>(x2, ln2_w, ln2_b, y2);
    // pin: 96 -> 384
    k_gemm<96, 384, false, 0><<<dim3(2048, 4), 256, 0, stream>>>(y2, Wpin, nullptr, h1);
    // grouped 3x3 + gelu gate
    k_dwgate<<<NPOS / 32, 192, 0, stream>>>(h1, dw_w, gated);
    // pout + residual(fp32) -> Fout
    k_gemm<192, 96, false, 1><<<dim3(2048, 1), 256, 0, stream>>>(gated, Wpout, x2, Fout);
    // NHWC -> NCHW final
    k_tout<<<NPOS / 64, 256, 0, stream>>>(Fout, out);
}

// Round 4
// 1154.978 us; speedup vs baseline: 2.2559x; 1.1483x over previous
//
#include <hip/hip_runtime.h>
#include <hip/hip_bf16.h>

#define NPOS 262144   // 4 * 256 * 256

typedef short bf16x8 __attribute__((ext_vector_type(8)));
typedef float f32x4 __attribute__((ext_vector_type(4)));

__device__ __forceinline__ unsigned short f2bf(float f) {
    union { float f; unsigned u; } v; v.f = f;
    unsigned r = v.u + 0x7fffu + ((v.u >> 16) & 1u);
    return (unsigned short)(r >> 16);
}
__device__ __forceinline__ float bf2f(unsigned short h) {
    union { unsigned u; float f; } v; v.u = ((unsigned)h) << 16;
    return v.f;
}
__device__ __forceinline__ float bflo(unsigned d) {
    union { unsigned u; float f; } v; v.u = d << 16;
    return v.f;
}
__device__ __forceinline__ float bfhi(unsigned d) {
    union { unsigned u; float f; } v; v.u = d & 0xffff0000u;
    return v.f;
}
__device__ __forceinline__ float gelu_tanh(float x) {
    float u = 0.7978845608028654f * (x + 0.044715f * x * x * x);
    float t = 1.0f - 2.0f / (__expf(2.0f * u) + 1.0f);
    return 0.5f * x * (1.0f + t);
}

// ---------------- utility ----------------
__global__ void k_fillz(float* __restrict__ p, int n) {
    int i = blockIdx.x * 256 + threadIdx.x;
    if (i < n) p[i] = 0.f;
}
__global__ void k_f32_to_bf16(const float* __restrict__ src, unsigned short* __restrict__ dst, int n) {
    int i = blockIdx.x * 256 + threadIdx.x;
    if (i < n) dst[i] = f2bf(src[i]);
}

// Combined qkv weight: Wc[tap][co][ci] = sum_k w2[co][k][tap] * w1[k][ci]
__global__ void k_combine_qkv(const float* __restrict__ w2, const float* __restrict__ w1,
        unsigned short* __restrict__ out) {
    int bx = blockIdx.x;           // 9*288
    int tap = bx / 288, co = bx % 288;
    int ci = threadIdx.x;          // 96
    const float* w2p = w2 + (size_t)co * 2592 + tap;
    float acc = 0.f;
    for (int k = 0; k < 288; k++)
        acc += w2p[k * 9] * w1[k * 96 + ci];
    out[((size_t)tap * 288 + co) * 96 + ci] = f2bf(acc);
}

// ---------------- LN1: NCHW fp32 -> xres (NHWC bf16) + y1 (NHWC bf16) ----------------
__global__ __launch_bounds__(256) void k_ln1(const float* __restrict__ x,
        const float* __restrict__ lnw, const float* __restrict__ lnb,
        unsigned short* __restrict__ xres, unsigned short* __restrict__ y1) {
    __shared__ float tile[96 * 65];
    __shared__ float smu[64], srs[64];
    const int t = threadIdx.x;
    const int p0 = blockIdx.x * 64;
    const int b = p0 >> 16, hw0 = p0 & 65535;
    #pragma unroll
    for (int i = 0; i < 24; i++) {
        int g = i * 256 + t;
        int c = g >> 6, pos = g & 63;
        tile[c * 65 + pos] = x[(size_t)(b * 96 + c) * 65536 + hw0 + pos];
    }
    __syncthreads();
    if (t < 64) {
        float s = 0.f, s2 = 0.f;
        for (int c = 0; c < 96; c++) { float v = tile[c * 65 + t]; s += v; s2 += v * v; }
        float mu = s * (1.0f / 96.0f);
        float var = s2 * (1.0f / 96.0f) - mu * mu;
        smu[t] = mu; srs[t] = rsqrtf(var + 1e-5f);
    }
    __syncthreads();
    #pragma unroll
    for (int i = 0; i < 12; i++) {
        int g2 = (i * 256 + t) * 2;
        int pos = g2 / 96, c = g2 % 96;
        float v0 = tile[c * 65 + pos], v1 = tile[(c + 1) * 65 + pos];
        float mu = smu[pos], rs = srs[pos];
        size_t o = (size_t)(p0 + pos) * 96 + c;
        *(unsigned*)(xres + o) = (unsigned)f2bf(v0) | ((unsigned)f2bf(v1) << 16);
        unsigned short a0 = f2bf((v0 - mu) * rs * lnw[c] + lnb[c]);
        unsigned short a1 = f2bf((v1 - mu) * rs * lnw[c + 1] + lnb[c + 1]);
        *(unsigned*)(y1 + o) = (unsigned)a0 | ((unsigned)a1 << 16);
    }
}

// ---------------- LN2: NHWC fp32 -> NHWC bf16 ----------------
__global__ __launch_bounds__(256) void k_ln2(const float* __restrict__ xin,
        const float* __restrict__ lnw, const float* __restrict__ lnb,
        unsigned short* __restrict__ y2) {
    __shared__ float tile[64 * 97];
    __shared__ float smu[64], srs[64];
    const int t = threadIdx.x;
    const int p0 = blockIdx.x * 64;
    #pragma unroll
    for (int i = 0; i < 24; i++) {
        int g = i * 256 + t;
        int pos = g / 96, c = g % 96;
        tile[pos * 97 + c] = xin[(size_t)p0 * 96 + g];
    }
    __syncthreads();
    if (t < 64) {
        float s = 0.f, s2 = 0.f;
        for (int c = 0; c < 96; c++) { float v = tile[t * 97 + c]; s += v; s2 += v * v; }
        float mu = s * (1.0f / 96.0f);
        float var = s2 * (1.0f / 96.0f) - mu * mu;
        smu[t] = mu; srs[t] = rsqrtf(var + 1e-5f);
    }
    __syncthreads();
    #pragma unroll
    for (int i = 0; i < 12; i++) {
        int g2 = (i * 256 + t) * 2;
        int pos = g2 / 96, c = g2 % 96;
        float mu = smu[pos], rs = srs[pos];
        unsigned short a0 = f2bf((tile[pos * 97 + c] - mu) * rs * lnw[c] + lnb[c]);
        unsigned short a1 = f2bf((tile[pos * 97 + c + 1] - mu) * rs * lnw[c + 1] + lnb[c + 1]);
        *(unsigned*)(y2 + (size_t)p0 * 96 + g2) = (unsigned)a0 | ((unsigned)a1 << 16);
    }
}

// ---------------- NHWC fp32 -> NCHW fp32 (final output) ----------------
__global__ __launch_bounds__(256) void k_tout(const float* __restrict__ xin, float* __restrict__ out) {
    __shared__ float tile[96 * 65];
    const int t = threadIdx.x;
    const int p0 = blockIdx.x * 64;
    const int b = p0 >> 16, hw0 = p0 & 65535;
    #pragma unroll
    for (int i = 0; i < 24; i++) {
        int g = i * 256 + t;
        int pos = g / 96, c = g % 96;
        tile[c * 65 + pos] = xin[(size_t)p0 * 96 + g];
    }
    __syncthreads();
    #pragma unroll
    for (int i = 0; i < 24; i++) {
        int g = i * 256 + t;
        int c = g >> 6, pos = g & 63;
        out[(size_t)(b * 96 + c) * 65536 + hw0 + pos] = tile[c * 65 + pos];
    }
}

// ---------------- MFMA GEMM: C[pos][co] = sum_k A[pos][k] * W[co][k] ----------------
template<int K, int NOUT, bool TAPS3, int EPI>
__global__ __launch_bounds__(256, 2) void k_gemm(
        const unsigned short* __restrict__ A, const unsigned short* __restrict__ W,
        const void* __restrict__ RES, void* __restrict__ OUT) {
    constexpr int KC = 96;
    constexpr int LDA = KC + 8;
    static_assert(K % KC == 0, "K multiple of 96");
    __shared__ unsigned short As[128 * LDA];
    __shared__ unsigned short Bs[96 * LDA];

    const int t = threadIdx.x;
    const int wv = t >> 6, lane = t & 63;
    const int quad = lane >> 4, lrow = lane & 15;
    const int p0 = blockIdx.x * 128;
    const int co0 = blockIdx.y * 96;

    f32x4 acc[2][6];
    f32x4 zero = {0.f, 0.f, 0.f, 0.f};
    #pragma unroll
    for (int i = 0; i < 2; i++)
        #pragma unroll
        for (int j = 0; j < 6; j++) acc[i][j] = zero;

    const int ntap = TAPS3 ? 9 : 1;
    for (int tap = 0; tap < ntap; tap++) {
        int dy = 0, dx = 0;
        if (TAPS3) {
            dy = tap / 3 - 1; dx = tap % 3 - 1;
            int h = (p0 >> 8) & 255;
            if ((unsigned)(h + dy) >= 256u) continue;
        }
        for (int kc = 0; kc < K / KC; kc++) {
            const int k0 = kc * KC;
            #pragma unroll
            for (int i = 0; i < 6; i++) {
                int g = i * 256 + t;
                int row = g / 12, u = g % 12;
                uint4 val = {0u, 0u, 0u, 0u};
                int p = p0 + row;
                bool ok = true;
                const unsigned short* src;
                if (TAPS3) {
                    int wc = p & 255;
                    ok = ((unsigned)(wc + dx) < 256u);
                    src = A + (size_t)(p + dy * 256 + dx) * K + k0 + u * 8;
                } else {
                    src = A + (size_t)p * K + k0 + u * 8;
                }
                if (ok) val = *(const uint4*)src;
                *(uint4*)(As + row * LDA + u * 8) = val;
            }
            for (int g = t; g < 1152; g += 256) {
                int row = g / 12, u = g % 12;
                const unsigned short* src = W + ((size_t)tap * NOUT + co0 + row) * K + k0 + u * 8;
                *(uint4*)(Bs + row * LDA + u * 8) = *(const uint4*)src;
            }
            __syncthreads();
            #pragma unroll
            for (int kk = 0; kk < 3; kk++) {
                bf16x8 a[2], b[6];
                #pragma unroll
                for (int mt = 0; mt < 2; mt++)
                    a[mt] = *(const bf16x8*)(As + (wv * 32 + mt * 16 + lrow) * LDA + kk * 32 + quad * 8);
                #pragma unroll
                for (int nt = 0; nt < 6; nt++)
                    b[nt] = *(const bf16x8*)(Bs + (nt * 16 + lrow) * LDA + kk * 32 + quad * 8);
                #pragma unroll
                for (int mt = 0; mt < 2; mt++)
                    #pragma unroll
                    for (int nt = 0; nt < 6; nt++)
                        acc[mt][nt] = __builtin_amdgcn_mfma_f32_16x16x32_bf16(a[mt], b[nt], acc[mt][nt], 0, 0, 0);
            }
            __syncthreads();
        }
    }

    if (EPI == 0) {
        #pragma unroll
        for (int mt = 0; mt < 2; mt++)
            #pragma unroll
            for (int nt = 0; nt < 6; nt++)
                #pragma unroll
                for (int r = 0; r < 4; r++) {
                    int m = wv * 32 + mt * 16 + quad * 4 + r;
                    int n = nt * 16 + lrow;
                    As[m * LDA + n] = f2bf(acc[mt][nt][r]);
                }
        __syncthreads();
        unsigned short* o = (unsigned short*)OUT;
        #pragma unroll
        for (int i = 0; i < 6; i++) {
            int g = i * 256 + t;
            int row = g / 12, u = g % 12;
            *(uint4*)(o + (size_t)(p0 + row) * NOUT + co0 + u * 8) = *(const uint4*)(As + row * LDA + u * 8);
        }
    } else {
        float* o = (float*)OUT;
        #pragma unroll
        for (int mt = 0; mt < 2; mt++)
            #pragma unroll
            for (int nt = 0; nt < 6; nt++)
                #pragma unroll
                for (int r = 0; r < 4; r++) {
                    int m = wv * 32 + mt * 16 + quad * 4 + r;
                    int n = nt * 16 + lrow;
                    size_t idx = (size_t)(p0 + m) * NOUT + co0 + n;
                    float res = (EPI == 1) ? ((const float*)RES)[idx]
                                           : bf2f(((const unsigned short*)RES)[idx]);
                    o[idx] = res + acc[mt][nt][r];
                }
    }
}

// ---------------- attention stats: per-block partial Gram + sq-norms (NO atomics) ----------------
__global__ __launch_bounds__(256) void k_attn_stats(const unsigned short* __restrict__ qkv,
        float* __restrict__ Gpart) {
    __shared__ unsigned short tt[192 * 68];
    const int t = threadIdx.x;
    const int bi = blockIdx.x;
    const int p0 = bi * 256;
    const int cq = t >> 4, ck = t & 15;
    float gacc[6] = {0, 0, 0, 0, 0, 0};
    float nacc = 0.f;
    for (int tl = 0; tl < 4; tl++) {
        const int pb = p0 + tl * 64;
        __syncthreads();
        #pragma unroll
        for (int i = 0; i < 6; i++) {
            int g = i * 256 + t;
            int u = g >> 6, row = g & 63;
            uint4 d = *(const uint4*)(qkv + (size_t)(pb + row) * 288 + u * 8);
            unsigned short v[8];
            *(uint4*)v = d;
            #pragma unroll
            for (int j = 0; j < 8; j++)
                tt[(u * 8 + j) * 68 + row] = v[j];
        }
        __syncthreads();
        #pragma unroll
        for (int hd = 0; hd < 6; hd++) {
            const unsigned short* qp = tt + (hd * 16 + cq) * 68;
            const unsigned short* kp = tt + (96 + hd * 16 + ck) * 68;
            float a = 0.f;
            #pragma unroll
            for (int pg = 0; pg < 16; pg++) {
                ushort4 q4 = *(const ushort4*)(qp + pg * 4);
                ushort4 k4 = *(const ushort4*)(kp + pg * 4);
                a += bf2f(q4.x) * bf2f(k4.x) + bf2f(q4.y) * bf2f(k4.y)
                   + bf2f(q4.z) * bf2f(k4.z) + bf2f(q4.w) * bf2f(k4.w);
            }
            gacc[hd] += a;
        }
        if (t < 192) {
            const unsigned short* cp = tt + t * 68;
            float a = 0.f;
            #pragma unroll
            for (int pg = 0; pg < 16; pg++) {
                ushort4 c4 = *(const ushort4*)(cp + pg * 4);
                a += bf2f(c4.x) * bf2f(c4.x) + bf2f(c4.y) * bf2f(c4.y)
                   + bf2f(c4.z) * bf2f(c4.z) + bf2f(c4.w) * bf2f(c4.w);
            }
            nacc += a;
        }
    }
    float* gp = Gpart + (size_t)bi * 1728;
    #pragma unroll
    for (int hd = 0; hd < 6; hd++) gp[hd * 256 + t] = gacc[hd];
    if (t < 192) gp[1536 + t] = nacc;
}

__global__ __launch_bounds__(256) void k_attn_reduce(const float* __restrict__ Gpart,
        float* __restrict__ G, float* __restrict__ nrm) {
    int idx = blockIdx.x * 256 + threadIdx.x;   // 0..6911
    int b = idx / 1728, j = idx % 1728;
    const float* src = Gpart + (size_t)(b * 256) * 1728 + j;
    float s = 0.f;
    for (int blk = 0; blk < 256; blk++) s += src[(size_t)blk * 1728];
    if (j < 1536) G[b * 1536 + j] = s;
    else nrm[b * 192 + (j - 1536)] = s;
}

// ---------------- softmax over 16-wide rows ----------------
__global__ void k_softmax(const float* __restrict__ G, const float* __restrict__ nrm,
        const float* __restrict__ scale, float* __restrict__ attnW) {
    int t = threadIdx.x; // 384 threads
    int bh = t >> 4, cq = t & 15;
    int b = bh / 6, hd = bh % 6;
    float qn = fmaxf(sqrtf(nrm[b * 192 + hd * 16 + cq]), 1e-12f);
    float l[16];
    float mx = -1e30f;
    #pragma unroll
    for (int ck = 0; ck < 16; ck++) {
        float kn = fmaxf(sqrtf(nrm[b * 192 + 96 + hd * 16 + ck]), 1e-12f);
        float v = G[(bh * 16 + cq) * 16 + ck] / (qn * kn) * scale[hd];
        l[ck] = v; mx = fmaxf(mx, v);
    }
    float s = 0.f;
    #pragma unroll
    for (int ck = 0; ck < 16; ck++) { l[ck] = __expf(l[ck] - mx); s += l[ck]; }
    float inv = 1.f / s;
    #pragma unroll
    for (int ck = 0; ck < 16; ck++) attnW[(bh * 16 + cq) * 16 + ck] = l[ck] * inv;
}

// ---------------- apply attention ----------------
__global__ __launch_bounds__(256) void k_apply(const unsigned short* __restrict__ qkv,
        const float* __restrict__ attnW, unsigned short* __restrict__ out) {
    __shared__ float aw[1536];
    const int t = threadIdx.x;
    const int p0 = blockIdx.x * 256;
    const int b = p0 >> 16;
    for (int i = t; i < 1536; i += 256) aw[i] = attnW[b * 1536 + i];
    __syncthreads();
    const int p = p0 + t;
    const unsigned short* vp = qkv + (size_t)p * 288 + 192;
    float v[96];
    #pragma unroll
    for (int i = 0; i < 12; i++) {
        uint4 d = *(const uint4*)(vp + i * 8);
        unsigned arr[4] = {d.x, d.y, d.z, d.w};
        #pragma unroll
        for (int j = 0; j < 4; j++) {
            v[i * 8 + j * 2]     = bf2f((unsigned short)(arr[j] & 0xffffu));
            v[i * 8 + j * 2 + 1] = bf2f((unsigned short)(arr[j] >> 16));
        }
    }
    unsigned short* outp = out + (size_t)p * 96;
    #pragma unroll
    for (int i = 0; i < 12; i++) {
        unsigned pk[4];
        #pragma unroll
        for (int j = 0; j < 4; j++) {
            float o2[2];
            #pragma unroll
            for (int e = 0; e < 2; e++) {
                int ch = i * 8 + j * 2 + e;
                int hd = ch >> 4;
                float a = 0.f;
                #pragma unroll
                for (int ck = 0; ck < 16; ck++) a += aw[ch * 16 + ck] * v[hd * 16 + ck];
                o2[e] = a;
            }
            pk[j] = (unsigned)f2bf(o2[0]) | ((unsigned)f2bf(o2[1]) << 16);
        }
        uint4 d; d.x = pk[0]; d.y = pk[1]; d.z = pk[2]; d.w = pk[3];
        *(uint4*)(outp + i * 8) = d;
    }
}

// ---------------- grouped 3x3 dwconv (2ch/group) + gelu gate ----------------
// Rewritten: weights in VGPRs (72/thread), sliding 3x3 window over 16
// consecutive positions (6 predicated dword loads/pos), no LDS at all.
__global__ __launch_bounds__(192) void k_dwgate(const unsigned short* __restrict__ h1,
        const float* __restrict__ dww, unsigned short* __restrict__ out) {
    const int t = threadIdx.x;            // 192
    const int c2 = t % 96, half = t / 96;
    const int pbase = blockIdx.x * 32 + half * 16;   // 16 consecutive positions
    const int h = (pbase >> 8) & 255;                // uniform per block
    const int w0 = pbase & 255;                      // multiple of 16

    // weights: wr[cb*18 + j*9 + tap]; cb: 0->o=2c2, 1->2c2+1, 2->192+2c2, 3->193+2c2
    float wr[72];
    {
        #pragma unroll
        for (int cb = 0; cb < 4; cb++) {
            int o = (cb & 1) + 2 * c2 + 192 * (cb >> 1);
            const float* src = dww + o * 18;
            #pragma unroll
            for (int k = 0; k < 9; k++) {
                float2 v = *(const float2*)(src + k * 2);
                wr[cb * 18 + k * 2] = v.x;
                wr[cb * 18 + k * 2 + 1] = v.y;
            }
        }
    }

    const bool hv0 = (h > 0), hv2 = (h < 255);
    // stream dword pointers at position pbase: s = dy*2 + part (part0: ch pair 2c2; part1: 192+2c2)
    const unsigned* bp[6];
    #pragma unroll
    for (int dy = 0; dy < 3; dy++) {
        long long rowoff = (long long)(pbase + (dy - 1) * 256) * 192;
        bp[dy * 2 + 0] = (const unsigned*)h1 + rowoff + c2;
        bp[dy * 2 + 1] = (const unsigned*)h1 + rowoff + 96 + c2;
    }
    const bool hvs[3] = { hv0, true, hv2 };

    // window: win[col 0..2][stream 0..5][elem 0..1]
    float win[3][6][2];
    #pragma unroll
    for (int s = 0; s < 6; s++) {
        bool hv = hvs[s >> 1];
        unsigned dl = (hv && w0 > 0) ? bp[s][-1] : 0u;
        unsigned dm = hv ? bp[s][0] : 0u;
        win[0][s][0] = bflo(dl); win[0][s][1] = bfhi(dl);
        win[1][s][0] = bflo(dm); win[1][s][1] = bfhi(dm);
    }

    unsigned* outp = (unsigned*)out + (size_t)pbase * 96 + c2;

    #pragma unroll
    for (int k = 0; k < 16; k++) {
        const bool wv = (w0 + k + 1 < 256);
        #pragma unroll
        for (int s = 0; s < 6; s++) {
            bool hv = hvs[s >> 1];
            unsigned dr = (hv && wv) ? bp[s][k + 1] : 0u;
            win[2][s][0] = bflo(dr); win[2][s][1] = bfhi(dr);
        }
        float a0 = 0.f, a1 = 0.f, a2 = 0.f, a3 = 0.f;
        #pragma unroll
        for (int dy = 0; dy < 3; dy++) {
            #pragma unroll
            for (int dx = 0; dx < 3; dx++) {
                const int tap = dy * 3 + dx;
                float i0 = win[dx][dy * 2][0],     i1 = win[dx][dy * 2][1];
                float i2 = win[dx][dy * 2 + 1][0], i3 = win[dx][dy * 2 + 1][1];
                a0 += wr[tap] * i0      + wr[9 + tap] * i1;
                a1 += wr[18 + tap] * i0 + wr[27 + tap] * i1;
                a2 += wr[36 + tap] * i2 + wr[45 + tap] * i3;
                a3 += wr[54 + tap] * i2 + wr[63 + tap] * i3;
            }
        }
        float g0 = gelu_tanh(a0) * a2;
        float g1 = gelu_tanh(a1) * a3;
        outp[k * 96] = (unsigned)f2bf(g0) | ((unsigned)f2bf(g1) << 16);
        // slide window
        #pragma unroll
        for (int s = 0; s < 6; s++) {
            win[0][s][0] = win[1][s][0]; win[0][s][1] = win[1][s][1];
            win[1][s][0] = win[2][s][0]; win[1][s][1] = win[2][s][1];
        }
    }
}

extern "C" void kernel_launch(void* const* d_in, const int* in_sizes, int n_in,
                              void* d_out, int out_size, void* d_ws, size_t ws_size,
                              hipStream_t stream) {
    const float* x      = (const float*)d_in[0];
    const float* ln1_w  = (const float*)d_in[1];
    const float* ln1_b  = (const float*)d_in[2];
    const float* qkv1_w = (const float*)d_in[3];
    const float* qkv2_w = (const float*)d_in[4];
    const float* proj_w = (const float*)d_in[5];
    const float* scale  = (const float*)d_in[6];
    const float* ln2_w  = (const float*)d_in[7];
    const float* ln2_b  = (const float*)d_in[8];
    const float* pin_w  = (const float*)d_in[9];
    const float* dw_w   = (const float*)d_in[10];
    const float* pout_w = (const float*)d_in[11];
    float* out = (float*)d_out;

    constexpr size_t SZ_WCOMB = (size_t)9 * 288 * 96 * 2;
    constexpr size_t SZ_WPROJ = (size_t)96 * 96 * 2;
    constexpr size_t SZ_WPIN  = (size_t)384 * 96 * 2;
    constexpr size_t SZ_WPOUT = (size_t)96 * 192 * 2;
    constexpr size_t SZ_STATS = (size_t)13056 * 4;
    constexpr size_t SZ_A = (size_t)NPOS * 96 * 2;             // 48 MB
    constexpr size_t SZ_B = (size_t)NPOS * 288 * 2;            // 144 MB
    constexpr size_t SZ_C = (size_t)NPOS * 96 * 4;             // 96 MB
    constexpr size_t OFF_WCOMB = 0;
    constexpr size_t OFF_WPROJ = OFF_WCOMB + SZ_WCOMB;
    constexpr size_t OFF_WPIN  = OFF_WPROJ + SZ_WPROJ;
    constexpr size_t OFF_WPOUT = OFF_WPIN + SZ_WPIN;
    constexpr size_t OFF_STATS = OFF_WPOUT + SZ_WPOUT;
    constexpr size_t OFF_A = OFF_STATS + SZ_STATS;
    constexpr size_t OFF_B = OFF_A + SZ_A;
    constexpr size_t OFF_C = OFF_B + SZ_B;
    constexpr size_t NEED = OFF_C + SZ_C;

    if (ws_size < NEED) {
        k_fillz<<<(out_size + 255) / 256, 256, 0, stream>>>(out, out_size);
        return;
    }

    char* ws = (char*)d_ws;
    unsigned short* Wcomb = (unsigned short*)(ws + OFF_WCOMB);
    unsigned short* Wproj = (unsigned short*)(ws + OFF_WPROJ);
    unsigned short* Wpin  = (unsigned short*)(ws + OFF_WPIN);
    unsigned short* Wpout = (unsigned short*)(ws + OFF_WPOUT);
    float* stats = (float*)(ws + OFF_STATS);
    float* G     = stats;
    float* nrm   = stats + 6144;
    float* attnW = stats + 6912;

    unsigned short* y1       = (unsigned short*)(ws + OFF_A);
    unsigned short* attn_out = (unsigned short*)(ws + OFF_A);
    unsigned short* qkv      = (unsigned short*)(ws + OFF_B);
    unsigned short* xres     = (unsigned short*)(ws + OFF_C);
    unsigned short* y2       = (unsigned short*)(ws + OFF_C + SZ_A);
    float*          Gpart    = (float*)(ws + OFF_C + SZ_A);
    unsigned short* h1       = (unsigned short*)(ws + OFF_A);
    unsigned short* gated    = (unsigned short*)(ws + OFF_C);
    float*          Fout     = (float*)(ws + OFF_A);
    float* x2 = out;

    // weight prep
    k_combine_qkv<<<9 * 288, 96, 0, stream>>>(qkv2_w, qkv1_w, Wcomb);
    k_f32_to_bf16<<<(96 * 96 + 255) / 256, 256, 0, stream>>>(proj_w, Wproj, 96 * 96);
    k_f32_to_bf16<<<(384 * 96 + 255) / 256, 256, 0, stream>>>(pin_w, Wpin, 384 * 96);
    k_f32_to_bf16<<<(96 * 192 + 255) / 256, 256, 0, stream>>>(pout_w, Wpout, 96 * 192);

    // LN1 (+ NCHW->NHWC), residual snapshot
    k_ln1<<<NPOS / 64, 256, 0, stream>>>(x, ln1_w, ln1_b, xres, y1);
    // combined qkv conv: 3x3, 96 -> 288
    k_gemm<96, 288, true, 0><<<dim3(2048, 3), 256, 0, stream>>>(y1, Wcomb, nullptr, qkv);
    // attention
    k_attn_stats<<<NPOS / 256, 256, 0, stream>>>(qkv, Gpart);
    k_attn_reduce<<<27, 256, 0, stream>>>(Gpart, G, nrm);
    k_softmax<<<1, 384, 0, stream>>>(G, nrm, scale, attnW);
    k_apply<<<NPOS / 256, 256, 0, stream>>>(qkv, attnW, attn_out);
    // proj + residual(bf16) -> x2 (NHWC fp32 in d_out)
    k_gemm<96, 96, false, 2><<<dim3(2048, 1), 256, 0, stream>>>(attn_out, Wproj, xres, x2);
    // LN2
    k_ln2<<<NPOS / 64, 256, 0, stream>>>(x2, ln2_w, ln2_b, y2);
    // pin: 96 -> 384
    k_gemm<96, 384, false, 0><<<dim3(2048, 4), 256, 0, stream>>>(y2, Wpin, nullptr, h1);
    // grouped 3x3 + gelu gate
    k_dwgate<<<NPOS / 32, 192, 0, stream>>>(h1, dw_w, gated);
    // pout + residual(fp32) -> Fout
    k_gemm<192, 96, false, 1><<<dim3(2048, 1), 256, 0, stream>>>(gated, Wpout, x2, Fout);
    // NHWC -> NCHW final
    k_tout<<<NPOS / 64, 256, 0, stream>>>(Fout, out);
}